// Round 2
// 320.831 us; speedup vs baseline: 1.0546x; 1.0546x over previous
//
#include <hip/hip_runtime.h>
#include <hip/hip_bf16.h>

// Single-head causal attention. B=512, T=256, C=384 (n_embd), H=64.
// scale = C^-0.5 (reference scales by n_embd, NOT head_size).
// Fused design: one block = one batch. Phase 1 computes q,k,v fragments into
// LDS (no global intermediate); phase 2 runs causal attention from LDS.

#define Bsz 512
#define Tt  256
#define Cc  384
#define Hh  64

typedef __attribute__((ext_vector_type(8))) short bf16x8;
typedef __attribute__((ext_vector_type(4))) float f32x4;

__device__ __forceinline__ unsigned short f2bf(float f) {
    unsigned int u = __float_as_uint(f);
    unsigned int r = (u + 0x7fffu + ((u >> 16) & 1u)) >> 16;   // RNE
    return (unsigned short)r;
}
__device__ __forceinline__ float bf2f(unsigned short b) {
    return __uint_as_float(((unsigned int)b) << 16);
}
__device__ __forceinline__ bf16x8 pack8(float4 a, float4 b) {
    union { __hip_bfloat162 h2[4]; bf16x8 v; } u;
    u.h2[0] = __float22bfloat162_rn(float2{a.x, a.y});
    u.h2[1] = __float22bfloat162_rn(float2{a.z, a.w});
    u.h2[2] = __float22bfloat162_rn(float2{b.x, b.y});
    u.h2[3] = __float22bfloat162_rn(float2{b.z, b.w});
    return u.v;
}
// async 16B global->LDS (direct-to-LDS DMA; dest must be uniform base + lane*16)
__device__ __forceinline__ void gload_lds16(const void* g, void* l) {
    __builtin_amdgcn_global_load_lds(
        (const __attribute__((address_space(1))) unsigned int*)g,
        (__attribute__((address_space(3))) unsigned int*)l, 16, 0, 0);
}

// ---------------- kernel 0: weights -> B-fragment order ------------------------
// wtf element ((kc*12+nt)*64 + lane)*8 + j = Wt[n=nt*16+(lane&15)][k=kc*32+(lane>>4)*8+j]
__global__ __launch_bounds__(256) void prep_kernel(const float* __restrict__ Wq,
                                                   const float* __restrict__ Wk,
                                                   const float* __restrict__ Wv,
                                                   unsigned short* __restrict__ wtf) {
    int idx = blockIdx.x * 256 + threadIdx.x;
    if (idx >= 192 * 384) return;
    int j = idx & 7;
    int l = (idx >> 3) & 63;
    int t = idx >> 9;                 // kc*12 + nt
    int kc = t / 12, nt = t - kc * 12;
    int n = nt * 16 + (l & 15);
    int k = kc * 32 + (l >> 4) * 8 + j;
    const float* W = (n < 64) ? Wq : ((n < 128) ? Wk : Wv);
    wtf[idx] = f2bf(W[k * 64 + (n & 63)]);
}

// ---------------- kernel 1: fused QKV + causal attention -----------------------
// 8 waves, 512 threads, one block per batch. LDS = 136 KB -> 1 block/CU, 2 waves/SIMD.
// Phase 1: x chunk [256][32] fp32 double-buffered via global_load_lds with
//   chunk-XOR swizzle (phys 16B-chunk = logical ^ (row&7)); counted vmcnt(4)
//   + raw s_barrier keeps next-chunk DMA in flight across the barrier (T3/T4).
//   B-fragments read global->reg (L1/L2-hot, 144 KB shared by all blocks),
//   issued BEFORE the stage DMAs so compiler vmcnt bookkeeping never drains them.
// LDS fragment layouts (identical to the old global qf/kf/vf minus batch offset):
//   q/k: [g=row>>4][s=d>>5][lane=((d>>3)&3)*16 + (row&15)][j=d&7]
//   v:   [ks2=t>>5][ht=d>>4][lane=((t>>3)&3)*16 + (d&15)][j=t&7]
// Phase 2: zero-barrier causal attention; wave w owns q-tiles {w, 15-w}
//   (exactly 9 key-steps each). Max-free softmax, divide at end.
__global__ __launch_bounds__(512, 2) void fused_kernel(
        const float* __restrict__ x,
        const float* __restrict__ bq,
        const float* __restrict__ bk,
        const float* __restrict__ bv,
        const unsigned short* __restrict__ wtf,
        float* __restrict__ out) {
    __shared__ float xl[2][256 * 32];             // 2 x 32 KB staging; buf0 reused for Q frags
    __shared__ unsigned short kl[16 * 128 * 8];   // 32 KB K fragments
    __shared__ unsigned short vl[8 * 4 * 64 * 8]; // 32 KB V fragments
    __shared__ unsigned short Pl[8 * 512];        // 8 KB per-wave P round-trip (swizzled)

    const int tid = threadIdx.x;
    const int w = tid >> 6, lane = tid & 63, quad = lane >> 4, cl = lane & 15;
    const int b = blockIdx.x;
    const int rb = b * 256;

    f32x4 acc[2][12];
#pragma unroll
    for (int rt = 0; rt < 2; ++rt)
#pragma unroll
        for (int nt = 0; nt < 12; ++nt) acc[rt][nt] = (f32x4){0.f, 0.f, 0.f, 0.f};

    // prologue: stage chunk 0 into buf0 (2048 slots of 16B; slot s -> row=s>>3, phys chunk=s&7)
#pragma unroll
    for (int i = 0; i < 4; ++i) {
        int s = i * 512 + tid;
        int row = s >> 3, cp = s & 7;
        int c = cp ^ (row & 7);                       // logical 16B chunk
        gload_lds16(x + (size_t)(rb + row) * Cc + c * 4, (char*)xl[0] + (size_t)s * 16);
    }

    for (int kc = 0; kc < 12; ++kc) {
        const int cur = kc & 1;
        // B fragments for THIS chunk, issued before next-chunk DMA:
        // after vmcnt(4) the only in-flight loads are the 4 next-chunk DMAs,
        // and the compiler's own waits for bfr (counted >= 4) never drain them.
        bf16x8 bfr[12];
#pragma unroll
        for (int nt = 0; nt < 12; ++nt)
            bfr[nt] = *(const bf16x8*)&wtf[((size_t)(kc * 12 + nt) * 64 + lane) * 8];
        if (kc < 11) {
            // stage chunk kc+1 into the other buffer (last read of that buffer was
            // chunk kc-1, fenced by the trailing barrier of the previous iteration)
#pragma unroll
            for (int i = 0; i < 4; ++i) {
                int s = i * 512 + tid;
                int row = s >> 3, cp = s & 7;
                int c = cp ^ (row & 7);
                gload_lds16(x + (size_t)(rb + row) * Cc + (kc + 1) * 32 + c * 4,
                            (char*)xl[cur ^ 1] + (size_t)s * 16);
            }
            asm volatile("s_waitcnt vmcnt(4)" ::: "memory");   // drain chunk kc, keep kc+1 in flight
        } else {
            asm volatile("s_waitcnt vmcnt(0)" ::: "memory");
        }
        __builtin_amdgcn_s_barrier();                          // chunk kc visible to all waves

        bf16x8 a[2];
#pragma unroll
        for (int rt = 0; rt < 2; ++rt) {
            int R = w * 32 + rt * 16 + cl;
            float4 lo = *(const float4*)&xl[cur][R * 32 + (((2 * quad) ^ (R & 7)) * 4)];
            float4 hi = *(const float4*)&xl[cur][R * 32 + (((2 * quad + 1) ^ (R & 7)) * 4)];
            a[rt] = pack8(lo, hi);
        }
#pragma unroll
        for (int nt = 0; nt < 12; ++nt) {
            acc[0][nt] = __builtin_amdgcn_mfma_f32_16x16x32_bf16(a[0], bfr[nt], acc[0][nt], 0, 0, 0);
            acc[1][nt] = __builtin_amdgcn_mfma_f32_16x16x32_bf16(a[1], bfr[nt], acc[1][nt], 0, 0, 0);
        }
        __builtin_amdgcn_s_barrier();   // reads of xl[cur] done before next iter's DMA into it
    }

    // epilogue: bias + bf16 cast, scatter into LDS fragment buffers
    // (Q overlays xl[0]; last read of buf0 was chunk 10 -> fenced by final barrier)
    unsigned short* qls = (unsigned short*)xl[0];
#pragma unroll
    for (int nt = 0; nt < 12; ++nt) {
        int col = nt * 16 + cl;
        if (nt < 4) {                                  // Q columns 0..63
            float bias = bq[col];
            int sh = col >> 5, qp = (col >> 3) & 3, j = col & 7;
#pragma unroll
            for (int rt = 0; rt < 2; ++rt) {
                int m0 = w * 32 + rt * 16 + quad * 4;
                int basei = (m0 >> 4) * 1024 + sh * 512 + qp * 128 + quad * 32 + j;
#pragma unroll
                for (int r = 0; r < 4; ++r)
                    qls[basei + r * 8] = f2bf(acc[rt][nt][r] + bias);
            }
        } else if (nt < 8) {                           // K columns 64..127
            int h = col & 63;
            float bias = bk[h];
            int sh = h >> 5, qp = (h >> 3) & 3, j = h & 7;
#pragma unroll
            for (int rt = 0; rt < 2; ++rt) {
                int m0 = w * 32 + rt * 16 + quad * 4;
                int basei = (m0 >> 4) * 1024 + sh * 512 + qp * 128 + quad * 32 + j;
#pragma unroll
                for (int r = 0; r < 4; ++r)
                    kl[basei + r * 8] = f2bf(acc[rt][nt][r] + bias);
            }
        } else {                                       // V columns 128..191
            int h = col - 128;
            float bias = bv[h];
            int ht = h >> 4, clp = h & 15;
#pragma unroll
            for (int rt = 0; rt < 2; ++rt) {
                int m0 = w * 32 + rt * 16 + quad * 4;
                int ks2 = m0 >> 5, qp = (m0 >> 3) & 3, j0 = m0 & 7;
                unsigned long long pk =
                      (unsigned long long)f2bf(acc[rt][nt][0] + bias)
                    | ((unsigned long long)f2bf(acc[rt][nt][1] + bias) << 16)
                    | ((unsigned long long)f2bf(acc[rt][nt][2] + bias) << 32)
                    | ((unsigned long long)f2bf(acc[rt][nt][3] + bias) << 48);
                *(unsigned long long*)&vl[(ks2 * 4 + ht) * 512 + qp * 128 + clp * 8 + j0] = pk;
            }
        }
    }
    __syncthreads();   // full drain: all fragment writes visible to all waves

    // ---------------- phase 2: causal attention from LDS ----------------------
    const float SL2E = 0.07362224f;          // log2(e) / sqrt(384)
    unsigned short* P = &Pl[w * 512];
#pragma unroll
    for (int ti = 0; ti < 2; ++ti) {
        const int W = ti ? (15 - w) : w;     // balanced pairing: 9 key-steps per wave
        const int qrow0 = W * 16;
        bf16x8 aq0 = *(const bf16x8*)&qls[(W * 128 + lane) * 8];
        bf16x8 aq1 = *(const bf16x8*)&qls[(W * 128 + 64 + lane) * 8];

        f32x4 o[4];
#pragma unroll
        for (int ht = 0; ht < 4; ++ht) o[ht] = (f32x4){0.f, 0.f, 0.f, 0.f};
        float rs[4] = {0.f, 0.f, 0.f, 0.f};

        const int nsteps = (qrow0 >> 5) + 1;
        for (int st = 0; st < nsteps; ++st) {
#pragma unroll
            for (int half = 0; half < 2; ++half) {
                int ct = st * 2 + half;      // 16-key tile
                bf16x8 b0 = *(const bf16x8*)&kl[(ct * 128 + lane) * 8];
                bf16x8 b1 = *(const bf16x8*)&kl[(ct * 128 + 64 + lane) * 8];
                f32x4 sc = (f32x4){0.f, 0.f, 0.f, 0.f};
                sc = __builtin_amdgcn_mfma_f32_16x16x32_bf16(aq0, b0, sc, 0, 0, 0);
                sc = __builtin_amdgcn_mfma_f32_16x16x32_bf16(aq1, b1, sc, 0, 0, 0);
                int key = ct * 16 + cl;
#pragma unroll
                for (int r = 0; r < 4; ++r) {
                    int row = quad * 4 + r;
                    float p = (key <= qrow0 + row) ? exp2f(sc[r] * SL2E) : 0.f;
                    unsigned short pb = f2bf(p);
                    rs[r] += bf2f(pb);
                    int k32 = half * 16 + cl;
                    int chunk = (k32 >> 3) ^ quad;           // XOR swizzle (row>>2 == quad)
                    P[row * 32 + chunk * 8 + (k32 & 7)] = pb;
                }
            }
            bf16x8 bvf[4];
#pragma unroll
            for (int ht = 0; ht < 4; ++ht)
                bvf[ht] = *(const bf16x8*)&vl[((st * 4 + ht) * 64 + lane) * 8];

            asm volatile("s_waitcnt lgkmcnt(0)" ::: "memory");   // wave-local P drain
            bf16x8 ap = *(const bf16x8*)((const char*)P + cl * 64 + ((quad ^ (cl >> 2)) & 3) * 16);
#pragma unroll
            for (int ht = 0; ht < 4; ++ht)
                o[ht] = __builtin_amdgcn_mfma_f32_16x16x32_bf16(ap, bvf[ht], o[ht], 0, 0, 0);
        }

        // normalize by row-sum (sum over the 16 key-lanes of each quad) and store
#pragma unroll
        for (int r = 0; r < 4; ++r) {
            float s = rs[r];
            s += __shfl_xor(s, 1);
            s += __shfl_xor(s, 2);
            s += __shfl_xor(s, 4);
            s += __shfl_xor(s, 8);
            float inv = 1.0f / s;
            int t = qrow0 + quad * 4 + r;
#pragma unroll
            for (int ht = 0; ht < 4; ++ht)
                out[((size_t)(b * Tt + t)) * Hh + ht * 16 + cl] = o[ht][r] * inv;
        }
    }
}

// ---------------- launcher ----------------------------------------------------
extern "C" void kernel_launch(void* const* d_in, const int* in_sizes, int n_in,
                              void* d_out, int out_size, void* d_ws, size_t ws_size,
                              hipStream_t stream) {
    const float* x  = (const float*)d_in[0];
    const float* Wq = (const float*)d_in[1];
    const float* bq = (const float*)d_in[2];
    const float* Wk = (const float*)d_in[3];
    const float* bk = (const float*)d_in[4];
    const float* Wv = (const float*)d_in[5];
    const float* bv = (const float*)d_in[6];
    float* out = (float*)d_out;

    unsigned short* wtf = (unsigned short*)d_ws;   // 144 KB fragment-order weights

    prep_kernel<<<288, 256, 0, stream>>>(Wq, Wk, Wv, wtf);
    fused_kernel<<<Bsz, 512, 0, stream>>>(x, bq, bk, bv, wtf, out);
}